// Round 11
// baseline (8245.692 us; speedup 1.0000x reference)
//
#include <hip/hip_runtime.h>
#include <cstdint>
#include <cstddef>

typedef __attribute__((ext_vector_type(8))) short short8;
typedef __attribute__((ext_vector_type(4))) float floatx4;

constexpr int kSeq = 512;
constexpr int kBatch = 256;
constexpr int kIn = 15;
constexpr int kH = 512;
constexpr int kG = 4 * kH;                      // 2048 gate cols, order i,f,g,o
constexpr int kRing = 17;                       // ring depth (> window 16)
constexpr size_t kHSlot = (size_t)kBatch * kH;  // elements per h slot
// LDS: 128 KB weights + 4 waves * 768 B scratch + control words.
// 135 KB caps occupancy at 1 block/CU => exactly 32 blocks per XCD.
constexpr size_t kShmemBytes = 131072 + 4096;

__device__ __forceinline__ unsigned short f2bf(float f) {
    union { float f; unsigned u; } v; v.f = f;
    unsigned u = v.u;
    return (unsigned short)((u + 0x7fffu + ((u >> 16) & 1u)) >> 16);
}

__device__ __forceinline__ float sigm(float x) { return 1.0f / (1.0f + __expf(-x)); }
__device__ __forceinline__ float tanh_(float x) { return 1.0f - 2.0f / (1.0f + __expf(2.0f * x)); }

// system/LLC write-through store (sc0 sc1): cross-XCD data + agent flags
#define LLC_STORE16(P, V)                                                     \
    asm volatile("global_store_dwordx4 %0, %1, off sc0 sc1"                   \
                 :: "v"(P), "v"(V) : "memory")
// XCD-local store (sc0): write-through L1 into this XCD's L2 (dirty line).
#define L2_STORE16(P, V)                                                      \
    asm volatile("global_store_dwordx4 %0, %1, off sc0"                       \
                 :: "v"(P), "v"(V) : "memory")
#define L2_STOREF(P, V)                                                       \
    asm volatile("global_store_dword %0, %1, off sc0"                         \
                 :: "v"(P), "v"(V) : "memory")

// sc0 load: forced L1 miss, served by this XCD's L2 (always current for
// lines written sc0 by blocks on the same XCD).
__device__ __forceinline__ int ld_flag_sc0(const int* p) {
    int v;
    asm volatile("global_load_dword %0, %1, off sc0\n\ts_waitcnt vmcnt(0)"
                 : "=v"(v) : "v"(p) : "memory");
    return v;
}
__device__ __forceinline__ short8 ld16_sc0(const unsigned short* p) {
    short8 v;
    asm volatile("global_load_dwordx4 %0, %1, off sc0" : "=v"(v) : "v"(p));
    return v;
}

// XCD-local flag wait, BOUNDED: lanes watch line (lane&31) via sc0 loads
// (local-L2 served). On timeout sets the sticky dead latch -> all later
// waits no-op and the kernel free-runs to completion (test fails with a
// mismatch instead of hanging — diagnostic, not fatal-to-container).
__device__ __forceinline__ void waitq(const int* flags, int tgt, int lane, int& fc, int& dead) {
    if (tgt <= 0 || dead) return;
    const int* myf = flags + (lane & 31) * 16;
    int spin = 0;
    while (!__all(fc >= tgt)) {
        if (fc < tgt) fc = ld_flag_sc0(myf);
        if (++spin > 20000) { dead = 1; return; }
        if (spin > 4096) __builtin_amdgcn_s_sleep(8);
    }
}
// Agent-scope flag wait (LLC), bounded, for the cross-XCD h1 edge.
__device__ __forceinline__ void waita(const int* flags, int tgt, int lane, int& fc, int& dead) {
    if (tgt <= 0 || dead) return;
    const int* myf = flags + (lane & 31) * 16;
    int spin = 0;
    while (!__all(fc >= tgt)) {
        if (fc < tgt)
            fc = __hip_atomic_load(myf, __ATOMIC_RELAXED, __HIP_MEMORY_SCOPE_AGENT);
        if (++spin > 20000) { dead = 1; return; }
        if (spin > 4096) __builtin_amdgcn_s_sleep(8);
    }
}

__global__ void k_conv(const float* __restrict__ src, unsigned short* __restrict__ dst, int n) {
    int i = blockIdx.x * blockDim.x + threadIdx.x;
    if (i < n) dst[i] = f2bf(src[i]);
}

__global__ void k_conv_pad(const float* __restrict__ src, unsigned short* __restrict__ dst, int rows) {
    int i = blockIdx.x * blockDim.x + threadIdx.x;
    if (i >= rows * 32) return;
    int r = i >> 5, k = i & 31;
    dst[i] = (k < kIn) ? f2bf(src[r * kIn + k]) : (unsigned short)0;
}

// XCD-LOCAL persistent kernel. Placement discovered at runtime:
//   xcc = s_getreg(HW_REG_XCC_ID)&7 (m09-verified); layer = xcc>=4 ? 2 : 1;
//   batch-group g = xcc&3; rid = per-XCD atomic counter (1 block/CU via
//   135KB LDS => exactly 32 blocks/XCD).
// L1 group g (XCD g): h1 recurrence via the XCD's OWN L2 (sc0 stores/loads,
//   no fences). Each step also stores an LLC copy (sc0sc1) for layer 2;
//   its drain is deferred to the top of the next step (vmcnt(1) locally,
//   full vmcnt(0)+block barrier before the f1c agent publish).
//   L1 throttles to <= ~13 steps ahead of layer-2 progress (< ring 17).
// L2 group g (XCD 4+g): h2 recurrence XCD-local (sc0). h1 consumed from the
//   LLC copy with sc0 loads + acquire-agent fence every 16 steps (ring 17 >
//   window 16 => each address re-read only across a fence).
// Cross-iteration self-init: each block zero-writes its own flag word and
//   its slot-16 ring region with sc0 (overwrites stale dirty L2 lines left
//   by the previous bench iteration — memset only fixes LLC/memory).
__global__ __launch_bounds__(256) void k_persist(
    const unsigned short* __restrict__ whh1b,
    const unsigned short* __restrict__ wih1b,
    const unsigned short* __restrict__ wih2b,
    const unsigned short* __restrict__ whh2b,
    const unsigned short* __restrict__ xb,
    const float* __restrict__ bih1, const float* __restrict__ bhh1,
    const float* __restrict__ bih2, const float* __restrict__ bhh2,
    unsigned short* __restrict__ h1loc,  // kRing slots (L1-XCD local)
    unsigned short* __restrict__ h1llc,  // kRing slots (LLC copies for L2)
    unsigned short* __restrict__ h2loc,  // kRing slots (L2-XCD local)
    float* __restrict__ h2f,
    int* __restrict__ flags,   // per group stride 4096 ints: f1loc@0, f2loc@512, f1c@1024, uprog@1536
    int* __restrict__ cnt)     // 8 ints: per-XCD block counter
{
    extern __shared__ unsigned short lw[];
    const int tid = (int)threadIdx.x;
    const int wave = tid >> 6;
    const int lane = tid & 63;
    const int lcol = lane & 15;
    const int quad = lane >> 4;

    unsigned xcc;
    asm("s_getreg_b32 %0, hwreg(HW_REG_XCC_ID)" : "=s"(xcc));
    xcc &= 7u;
    const bool is2 = xcc >= 4;
    const int g = (int)(xcc & 3u);

    int* ridp = (int*)(lw + 67072);
    if (tid == 0) *ridp = atomicAdd(cnt + xcc, 1);
    __syncthreads();
    const int rid_raw = *ridp;
    int dead = (rid_raw >= 32) ? 1 : 0;   // mapping assumption broke -> free-run
    const int rid = rid_raw & 31;
    const int j0 = rid << 4;

    const int m0 = (g << 6) + wave * 16;
    const int arow = m0 + lcol;
    const int koff = quad * 8;

    int* F = flags + g * 4096;
    int* f1loc = F;
    int* f2loc = F + 512;
    int* f1c   = F + 1024;
    int* uprog = F + 1536;
    int* myflag = (is2 ? f2loc : f1loc) + rid * 16;
    unsigned short* scr = lw + 65536 + wave * 384;   // 16 rows x stride-24

    // ---- self-init: overwrite stale dirty L2 lines from prior iteration ----
    {
        unsigned short* ring = is2 ? h2loc : h1loc;
        short8 z = (short8){0, 0, 0, 0, 0, 0, 0, 0};
        if (lane < 32) {   // slot 16 = h[-1] = zeros (this block's write region)
            int row = lane >> 1, seg = lane & 1;
            unsigned short* zp = ring + (size_t)16 * kHSlot
                                 + (size_t)(m0 + row) * kH + j0 + seg * 8;
            L2_STORE16(zp, z);
        }
        if (tid == 0) L2_STOREF(myflag, 0);
        asm volatile("s_waitcnt vmcnt(0)" ::: "memory");
    }

    // ---- stage weight slices into LDS, fragment-linear layout ----
    if (!is2) {
        for (int i = tid; i < 4096; i += 256) {
            int ln = i >> 6, gg = ln >> 4, u = ln & 15;
            int c = i & 63, kk = c >> 2, qd = c & 3;
            *(short8*)&lw[((gg * 16 + kk) << 9) + ((qd * 16 + u) << 3)] =
                *(const short8*)&whh1b[(size_t)((gg << 9) + j0 + u) * kH + c * 8];
        }
        for (int i = tid; i < 256; i += 256) {
            int ln = i >> 2, gg = ln >> 4, u = ln & 15;
            int qd = i & 3;
            *(short8*)&lw[((64 + gg) << 9) + ((qd * 16 + u) << 3)] =
                *(const short8*)&wih1b[((gg << 9) + j0 + u) * 32 + qd * 8];
        }
    } else {
        for (int i = tid; i < 4096; i += 256) {
            int ln = i >> 6, gg = ln >> 4, u = ln & 15;
            int c = i & 63, kk = c >> 2, qd = c & 3;
            int dst = ((gg * 16 + kk) << 9) + ((qd * 16 + u) << 3);
            size_t src = (size_t)((gg << 9) + j0 + u) * kH + c * 8;
            *(short8*)&lw[dst] = *(const short8*)&wih2b[src];             // slabs 0..63
            *(short8*)&lw[dst + (64 << 9)] = *(const short8*)&whh2b[src]; // slabs 64..127
        }
    }
    float bsum[4];
#pragma unroll
    for (int gg = 0; gg < 4; ++gg) {
        int n = (gg << 9) + j0 + lcol;
        bsum[gg] = is2 ? (bih2[n] + bhh2[n]) : (bih1[n] + bhh1[n]);
    }
    __syncthreads();

    float creg[4] = {0.f, 0.f, 0.f, 0.f};

    if (!is2) {
        int fc1 = 0, upc = 0;
        for (int s = 0; s < kSeq; ++s) {
            // throttle: stay < ring-17 ahead of layer-2 progress (bounded)
            if ((s & 3) == 0 && s >= 12 && !dead) {
                int spin = 0;
                while (upc < s - 10) {
                    upc = __hip_atomic_load(uprog, __ATOMIC_RELAXED, __HIP_MEMORY_SCOPE_AGENT);
                    if (++spin > 20000) { dead = 1; break; }
                    if (spin > 4096) __builtin_amdgcn_s_sleep(8);
                }
            }
            floatx4 acc[4];
#pragma unroll
            for (int gg = 0; gg < 4; ++gg)
                acc[gg] = (floatx4){bsum[gg], bsum[gg], bsum[gg], bsum[gg]};

            short8 ax = *(const short8*)(xb + ((size_t)s * kBatch + arow) * 32 + koff);

            waitq(f1loc, s, lane, fc1, dead);          // peers done s-1 (local L2)
            const unsigned short* hp = h1loc + (size_t)((s + 16) % kRing) * kHSlot
                                       + (size_t)arow * kH + koff;   // h1[s-1]
            short8 a[16];
#pragma unroll
            for (int kk = 0; kk < 16; ++kk) a[kk] = ld16_sc0(hp + kk * 32);
            asm volatile("s_waitcnt vmcnt(0)" ::: "memory");  // loads done + step-(s-1) LLC stores drained
            __builtin_amdgcn_sched_barrier(0);
            __syncthreads();   // ALL waves drained their LLC stores
            if (tid == 0 && s > 0)
                __hip_atomic_store(f1c + rid * 16, s,
                                   __ATOMIC_RELAXED, __HIP_MEMORY_SCOPE_AGENT);
#pragma unroll
            for (int kk = 0; kk < 16; ++kk) {
#pragma unroll
                for (int gg = 0; gg < 4; ++gg) {
                    short8 b = *(const short8*)&lw[((gg * 16 + kk) << 9) + (lane << 3)];
                    acc[gg] = __builtin_amdgcn_mfma_f32_16x16x32_bf16(a[kk], b, acc[gg], 0, 0, 0);
                }
            }
#pragma unroll
            for (int gg = 0; gg < 4; ++gg) {
                short8 b = *(const short8*)&lw[((64 + gg) << 9) + (lane << 3)];
                acc[gg] = __builtin_amdgcn_mfma_f32_16x16x32_bf16(ax, b, acc[gg], 0, 0, 0);
            }

            // epilogue: activations -> per-wave LDS transpose -> stores
            const size_t sw = (size_t)(s % kRing) * kHSlot;
#pragma unroll
            for (int r = 0; r < 4; ++r) {
                int row = quad * 4 + r;
                float gi = acc[0][r], gf = acc[1][r], gv = acc[2][r], go = acc[3][r];
                float cn = sigm(gf) * creg[r] + sigm(gi) * tanh_(gv);
                float hn = sigm(go) * tanh_(cn);
                creg[r] = cn;
                scr[row * 24 + lcol] = f2bf(hn);
            }
            if (lane < 32) {
                int row = lane >> 1, seg = lane & 1;
                short8 v = *(short8*)&scr[row * 24 + seg * 8];
                size_t off = sw + (size_t)(m0 + row) * kH + j0 + seg * 8;
                L2_STORE16(h1loc + off, v);          // local copy (fast L2 ack)
                LLC_STORE16(h1llc + off, v);         // LLC copy (drains later)
            }
            asm volatile("s_waitcnt vmcnt(1)" ::: "memory");  // local store acked; LLC in flight
            __syncthreads();
            if (tid == 0) L2_STOREF(f1loc + rid * 16, s + 1);
        }
        asm volatile("s_waitcnt vmcnt(0)" ::: "memory");
        __syncthreads();
        if (tid == 0)
            __hip_atomic_store(f1c + rid * 16, kSeq,
                               __ATOMIC_RELAXED, __HIP_MEMORY_SCOPE_AGENT);
    } else {
        int fc1 = 0, fc2 = 0;
        for (int u = 0; u < kSeq; ++u) {
            if ((u & 15) == 0)       // window fence for the h1llc edge
                __builtin_amdgcn_fence(__ATOMIC_ACQUIRE, "agent");
            floatx4 acc[4];
#pragma unroll
            for (int gg = 0; gg < 4; ++gg)
                acc[gg] = (floatx4){bsum[gg], bsum[gg], bsum[gg], bsum[gg]};

            waitq(f2loc, u, lane, fc2, dead);          // peers done u-1 (local L2)
            const unsigned short* hp2 = h2loc + (size_t)((u + 16) % kRing) * kHSlot
                                        + (size_t)arow * kH + koff;  // h2[u-1]
            short8 a[16];
#pragma unroll
            for (int kk = 0; kk < 16; ++kk) a[kk] = ld16_sc0(hp2 + kk * 32);
            asm volatile("s_waitcnt vmcnt(0)" ::: "memory");
            __builtin_amdgcn_sched_barrier(0);
#pragma unroll
            for (int kk = 0; kk < 16; ++kk) {
#pragma unroll
                for (int gg = 0; gg < 4; ++gg) {
                    short8 b = *(const short8*)&lw[((64 + gg * 16 + kk) << 9) + (lane << 3)];
                    acc[gg] = __builtin_amdgcn_mfma_f32_16x16x32_bf16(a[kk], b, acc[gg], 0, 0, 0);
                }
            }

            waita(f1c, u + 1, lane, fc1, dead);        // L1 done step u (LLC flag)
            const unsigned short* hp1 = h1llc + (size_t)(u % kRing) * kHSlot
                                        + (size_t)arow * kH + koff;  // h1[u]
#pragma unroll
            for (int kk = 0; kk < 16; ++kk) a[kk] = ld16_sc0(hp1 + kk * 32);
            asm volatile("s_waitcnt vmcnt(0)" ::: "memory");
            __builtin_amdgcn_sched_barrier(0);
#pragma unroll
            for (int kk = 0; kk < 16; ++kk) {
#pragma unroll
                for (int gg = 0; gg < 4; ++gg) {
                    short8 b = *(const short8*)&lw[((gg * 16 + kk) << 9) + (lane << 3)];
                    acc[gg] = __builtin_amdgcn_mfma_f32_16x16x32_bf16(a[kk], b, acc[gg], 0, 0, 0);
                }
            }

            const size_t sw = (size_t)(u % kRing) * kHSlot;
            const int j = j0 + lcol;
#pragma unroll
            for (int r = 0; r < 4; ++r) {
                int row = quad * 4 + r;
                float gi = acc[0][r], gf = acc[1][r], gv = acc[2][r], go = acc[3][r];
                float cn = sigm(gf) * creg[r] + sigm(gi) * tanh_(gv);
                float hn = sigm(go) * tanh_(cn);
                creg[r] = cn;
                scr[row * 24 + lcol] = f2bf(hn);
                if (u == kSeq - 1) h2f[(size_t)(m0 + row) * kH + j] = hn;
            }
            if (lane < 32) {
                int row = lane >> 1, seg = lane & 1;
                short8 v = *(short8*)&scr[row * 24 + seg * 8];
                size_t off = sw + (size_t)(m0 + row) * kH + j0 + seg * 8;
                L2_STORE16(h2loc + off, v);
            }
            asm volatile("s_waitcnt vmcnt(0)" ::: "memory");   // local-only drain
            __syncthreads();
            if (tid == 0) {
                L2_STOREF(f2loc + rid * 16, u + 1);
                if (rid == 0)
                    __hip_atomic_store(uprog, u + 1,
                                       __ATOMIC_RELAXED, __HIP_MEMORY_SCOPE_AGENT);
            }
        }
    }
}

__global__ __launch_bounds__(64) void k_head(
    const float* __restrict__ h2f, const float* __restrict__ fc1w,
    const float* __restrict__ fc1b, const float* __restrict__ fcw,
    const float* __restrict__ fcb, float* __restrict__ out)
{
    int m = blockIdx.x;
    int j = threadIdx.x;
    const float* hr = h2f + (size_t)m * kH;
    const float* wr = fc1w + (size_t)j * kH;
    float sacc = 0.f;
    for (int k = 0; k < kH; ++k) sacc += fmaxf(hr[k], 0.f) * wr[k];
    float rv = fmaxf(sacc + fc1b[j], 0.f) * fcw[j];
#pragma unroll
    for (int off = 32; off >= 1; off >>= 1) rv += __shfl_down(rv, off);
    if (j == 0) out[m] = 2.0f * (rv + fcb[0]);
}

extern "C" void kernel_launch(void* const* d_in, const int* in_sizes, int n_in,
                              void* d_out, int out_size, void* d_ws, size_t ws_size,
                              hipStream_t stream) {
    const float* x    = (const float*)d_in[0];
    const float* Wih1 = (const float*)d_in[1];
    const float* Whh1 = (const float*)d_in[2];
    const float* bih1 = (const float*)d_in[3];
    const float* bhh1 = (const float*)d_in[4];
    const float* Wih2 = (const float*)d_in[5];
    const float* Whh2 = (const float*)d_in[6];
    const float* bih2 = (const float*)d_in[7];
    const float* bhh2 = (const float*)d_in[8];
    const float* fc1w = (const float*)d_in[9];
    const float* fc1b = (const float*)d_in[10];
    const float* fcw  = (const float*)d_in[11];
    const float* fcb  = (const float*)d_in[12];
    float* out = (float*)d_out;

    char* p = (char*)d_ws;
    auto take = [&](size_t bytes) -> char* {
        char* r = p;
        p += (bytes + 255) & ~(size_t)255;
        return r;
    };
    unsigned short* whh1b = (unsigned short*)take((size_t)kG * kH * 2);
    unsigned short* wih2b = (unsigned short*)take((size_t)kG * kH * 2);
    unsigned short* whh2b = (unsigned short*)take((size_t)kG * kH * 2);
    unsigned short* wih1b = (unsigned short*)take((size_t)kG * 32 * 2);
    unsigned short* xb    = (unsigned short*)take((size_t)kSeq * kBatch * 32 * 2);
    char* state = p;
    unsigned short* h1loc = (unsigned short*)take((size_t)kRing * kHSlot * 2);
    unsigned short* h1llc = (unsigned short*)take((size_t)kRing * kHSlot * 2);
    unsigned short* h2loc = (unsigned short*)take((size_t)kRing * kHSlot * 2);
    int* flags = (int*)take(65536);
    int* cnt   = (int*)take(256);
    size_t state_bytes = (size_t)((char*)cnt + 256 - state);
    float* h2f = (float*)take((size_t)kBatch * kH * 4);

    hipMemsetAsync(state, 0, state_bytes, stream);

    int n = kG * kH;
    k_conv<<<(n + 255) / 256, 256, 0, stream>>>(Whh1, whh1b, n);
    k_conv<<<(n + 255) / 256, 256, 0, stream>>>(Wih2, wih2b, n);
    k_conv<<<(n + 255) / 256, 256, 0, stream>>>(Whh2, whh2b, n);
    k_conv_pad<<<(kG * 32 + 255) / 256, 256, 0, stream>>>(Wih1, wih1b, kG);
    k_conv_pad<<<(kSeq * kBatch * 32 + 255) / 256, 256, 0, stream>>>(x, xb, kSeq * kBatch);

    hipFuncSetAttribute((const void*)k_persist,
                        hipFuncAttributeMaxDynamicSharedMemorySize, (int)kShmemBytes);
    void* args[] = {&whh1b, &wih1b, &wih2b, &whh2b, &xb,
                    (void*)&bih1, (void*)&bhh1, (void*)&bih2, (void*)&bhh2,
                    &h1loc, &h1llc, &h2loc, &h2f, &flags, &cnt};
    hipError_t e = hipLaunchCooperativeKernel((const void*)k_persist, dim3(256), dim3(256),
                                              args, (unsigned)kShmemBytes, stream);
    if (e != hipSuccess) {
        k_persist<<<256, 256, kShmemBytes, stream>>>(
            whh1b, wih1b, wih2b, whh2b, xb, bih1, bhh1, bih2, bhh2,
            h1loc, h1llc, h2loc, h2f, flags, cnt);
    }

    k_head<<<kBatch, 64, 0, stream>>>(h2f, fc1w, fc1b, fcw, fcb, out);
}

// Round 13
// 3965.786 us; speedup vs baseline: 2.0792x; 2.0792x over previous
//
#include <hip/hip_runtime.h>
#include <cstdint>
#include <cstddef>

typedef __attribute__((ext_vector_type(8))) short short8;
typedef __attribute__((ext_vector_type(4))) float floatx4;

constexpr int kSeq = 512;
constexpr int kBatch = 256;
constexpr int kIn = 15;
constexpr int kH = 512;
constexpr int kG = 4 * kH;                      // 2048 gate cols, order i,f,g,o
constexpr int kRing = 33;                       // ring depth (> window 32)
constexpr int kWinMask = 31;                    // rendezvous window 32
constexpr size_t kHSlot = (size_t)kBatch * kH;  // elements per h slot
// LDS: 128 KB weights (fragment-linear) + 4 waves * 768 B transpose scratch
constexpr size_t kShmemBytes = 131072 + 4096;

__device__ __forceinline__ unsigned short f2bf(float f) {
    union { float f; unsigned u; } v; v.f = f;
    unsigned u = v.u;
    return (unsigned short)((u + 0x7fffu + ((u >> 16) & 1u)) >> 16);
}

__device__ __forceinline__ float sigm(float x) { return 1.0f / (1.0f + __expf(-x)); }
__device__ __forceinline__ float tanh_(float x) { return 1.0f - 2.0f / (1.0f + __expf(2.0f * x)); }

// 16-B write-through store (LLC always current; h never dirty in any L2)
#define LLC_STORE16(P, V)                                                     \
    asm volatile("global_store_dwordx4 %0, %1, off sc0 sc1"                   \
                 :: "v"(P), "v"(V) : "memory")

// ALL-WAVE poll with BOUNDED busy-spin (r5-proven, ties best): every wave
// independently watches the 32 flags (lanes 0..31, one 64B line each). Spin
// minimizes observe granularity; past 4096 iterations degrade to s_sleep(8)
// so pathological regimes are self-limiting. fc caches the monotone flag —
// a satisfied wait does zero memory ops. No broadcast barrier needed.
__device__ __forceinline__ void waitf(const int* flags, int tgt, int lane, int& fc) {
    if (tgt <= 0) return;
    bool watch = (lane < 32);
    if (__all(!watch || fc >= tgt)) return;
    int spin = 0;
    for (;;) {
        if (watch && fc < tgt)
            fc = __hip_atomic_load(flags + lane * 16,
                                   __ATOMIC_RELAXED, __HIP_MEMORY_SCOPE_AGENT);
        if (__all(!watch || fc >= tgt)) return;
        if (++spin > 4096) __builtin_amdgcn_s_sleep(8);
    }
}

__global__ void k_conv(const float* __restrict__ src, unsigned short* __restrict__ dst, int n) {
    int i = blockIdx.x * blockDim.x + threadIdx.x;
    if (i < n) dst[i] = f2bf(src[i]);
}

__global__ void k_conv_pad(const float* __restrict__ src, unsigned short* __restrict__ dst, int rows) {
    int i = blockIdx.x * blockDim.x + threadIdx.x;
    if (i >= rows * 32) return;
    int r = i >> 5, k = i & 31;
    dst[i] = (k < kIn) ? f2bf(src[r * kIn + k]) : (unsigned short)0;
}

// Persistent kernel (r5 skeleton, window 32 / ring 33).
// group g = blockIdx&3 (64 batch rows, 2-XCD-affine under RR dispatch);
// role = blockIdx>>2: 0..31 layer-1, 32..63 layer-2 (16 h-cols each).
// h1/h2: 33-slot rings. Producers: sc0sc1 write-through. Consumers: PLAIN
// CACHED loads (redundancy absorbed by per-XCD L2/L1), made safe by a
// group rendezvous + agent acquire fence every 32 steps:
//   - rendezvous at boundary B waits f1>=B && f2>=B  => all reads for steps
//     <B are complete before any fence;
//   - any two reads of the same ring address are >=33 steps apart (ring 33),
//     and a multiple-of-32 boundary always falls between them, so each
//     reader fences between old-value and new-value reads.
// Flags: one per 64B line (f1[32] @ +0, stride 16 ints; f2 @ +512 ints).
// All waves poll independently — the only per-step block barrier is the one
// before the tid==0 flag publish (all waves' stores must be drained first).
__global__ __launch_bounds__(256) void k_persist(
    const unsigned short* __restrict__ whh1b,
    const unsigned short* __restrict__ wih1b,
    const unsigned short* __restrict__ wih2b,
    const unsigned short* __restrict__ whh2b,
    const unsigned short* __restrict__ xb,
    const float* __restrict__ bih1, const float* __restrict__ bhh1,
    const float* __restrict__ bih2, const float* __restrict__ bhh2,
    unsigned short* __restrict__ h1r,   // kRing slots of kBatch*kH
    unsigned short* __restrict__ h2r,   // kRing slots of kBatch*kH
    float* __restrict__ h2f,
    int* __restrict__ flags)            // per group: f1[32] @ +0, f2[32] @ +512 ints
{
    extern __shared__ unsigned short lw[];
    const int bid = blockIdx.x;
    const int g = bid & 3;
    const int role = bid >> 2;
    const bool is2 = role >= 32;
    const int rid = role & 31;
    const int j0 = rid << 4;
    const int tid = (int)threadIdx.x;
    const int wave = tid >> 6;
    const int lane = tid & 63;
    const int lcol = lane & 15;
    const int quad = lane >> 4;
    const int m0 = (g << 6) + wave * 16;
    const int arow = m0 + lcol;
    const int koff = quad * 8;

    int* f1 = flags + g * 1024;
    int* f2 = f1 + 512;
    int* myflag = (is2 ? f2 : f1) + rid * 16;
    unsigned short* scr = lw + 65536 + wave * 384;   // 16 rows x stride-24 elems

    // ---- stage weight slices into LDS, fragment-linear layout ----
    if (!is2) {
        for (int i = tid; i < 4096; i += 256) {
            int ln = i >> 6, gg = ln >> 4, u = ln & 15;
            int c = i & 63, kk = c >> 2, qd = c & 3;
            *(short8*)&lw[((gg * 16 + kk) << 9) + ((qd * 16 + u) << 3)] =
                *(const short8*)&whh1b[(size_t)((gg << 9) + j0 + u) * kH + c * 8];
        }
        for (int i = tid; i < 256; i += 256) {
            int ln = i >> 2, gg = ln >> 4, u = ln & 15;
            int qd = i & 3;
            *(short8*)&lw[((64 + gg) << 9) + ((qd * 16 + u) << 3)] =
                *(const short8*)&wih1b[((gg << 9) + j0 + u) * 32 + qd * 8];
        }
    } else {
        for (int i = tid; i < 4096; i += 256) {
            int ln = i >> 6, gg = ln >> 4, u = ln & 15;
            int c = i & 63, kk = c >> 2, qd = c & 3;
            int dst = ((gg * 16 + kk) << 9) + ((qd * 16 + u) << 3);
            size_t src = (size_t)((gg << 9) + j0 + u) * kH + c * 8;
            *(short8*)&lw[dst] = *(const short8*)&wih2b[src];
            *(short8*)&lw[dst + (64 << 9)] = *(const short8*)&whh2b[src];
        }
    }
    float bsum[4];
#pragma unroll
    for (int gg = 0; gg < 4; ++gg) {
        int n = (gg << 9) + j0 + lcol;
        bsum[gg] = is2 ? (bih2[n] + bhh2[n]) : (bih1[n] + bhh1[n]);
    }
    __syncthreads();

    float creg[4] = {0.f, 0.f, 0.f, 0.f};
    int fc1 = 0, fc2 = 0;   // per-thread flag caches

    if (!is2) {
        for (int s = 0; s < kSeq; ++s) {
            if ((s & kWinMask) == 0) {   // window rendezvous + cache invalidate
                waitf(f1, s, lane, fc1);
                waitf(f2, s, lane, fc2);
                __builtin_amdgcn_fence(__ATOMIC_ACQUIRE, "agent");
            }
            floatx4 acc[4];
#pragma unroll
            for (int gg = 0; gg < 4; ++gg)
                acc[gg] = (floatx4){bsum[gg], bsum[gg], bsum[gg], bsum[gg]};

            short8 ax = *(const short8*)(xb + ((size_t)s * kBatch + arow) * 32 + koff);

            waitf(f1, s, lane, fc1);                    // peers done s-1
            const unsigned short* hp = h1r + (size_t)((s + kRing - 1) % kRing) * kHSlot
                                       + (size_t)arow * kH + koff;   // h1[s-1]
            short8 a[16];
#pragma unroll
            for (int kk = 0; kk < 16; ++kk) a[kk] = *(const short8*)(hp + kk * 32);
#pragma unroll
            for (int kk = 0; kk < 16; ++kk) {
#pragma unroll
                for (int gg = 0; gg < 4; ++gg) {
                    short8 b = *(const short8*)&lw[((gg * 16 + kk) << 9) + (lane << 3)];
                    acc[gg] = __builtin_amdgcn_mfma_f32_16x16x32_bf16(a[kk], b, acc[gg], 0, 0, 0);
                }
            }
#pragma unroll
            for (int gg = 0; gg < 4; ++gg) {
                short8 b = *(const short8*)&lw[((64 + gg) << 9) + (lane << 3)];
                acc[gg] = __builtin_amdgcn_mfma_f32_16x16x32_bf16(ax, b, acc[gg], 0, 0, 0);
            }

            // epilogue: activations -> per-wave LDS transpose -> 16B WT stores
            // (scr is wave-private: compiler's lgkmcnt orders write->read)
            unsigned short* hw = h1r + (size_t)(s % kRing) * kHSlot;
#pragma unroll
            for (int r = 0; r < 4; ++r) {
                int row = quad * 4 + r;
                float gi = acc[0][r], gf = acc[1][r], ggv = acc[2][r], go = acc[3][r];
                float cn = sigm(gf) * creg[r] + sigm(gi) * tanh_(ggv);
                float hn = sigm(go) * tanh_(cn);
                creg[r] = cn;
                scr[row * 24 + lcol] = f2bf(hn);
            }
            if (lane < 32) {
                int row = lane >> 1, seg = lane & 1;
                short8 v = *(short8*)&scr[row * 24 + seg * 8];
                unsigned short* gp = hw + (size_t)(m0 + row) * kH + j0 + seg * 8;
                LLC_STORE16(gp, v);
            }
            __builtin_amdgcn_s_waitcnt(0);
            __syncthreads();
            if (tid == 0)
                __hip_atomic_store(myflag, s + 1,
                                   __ATOMIC_RELAXED, __HIP_MEMORY_SCOPE_AGENT);
        }
    } else {
        for (int u = 0; u < kSeq; ++u) {
            if ((u & kWinMask) == 0) {   // window rendezvous + cache invalidate
                waitf(f1, u, lane, fc1);
                waitf(f2, u, lane, fc2);
                __builtin_amdgcn_fence(__ATOMIC_ACQUIRE, "agent");
            }
            floatx4 acc[4];
#pragma unroll
            for (int gg = 0; gg < 4; ++gg)
                acc[gg] = (floatx4){bsum[gg], bsum[gg], bsum[gg], bsum[gg]};

            waitf(f2, u, lane, fc2);                    // peers done u-1

            // h2[u-1] GEMM first (hides under L1's tail)
            const unsigned short* hp2 = h2r + (size_t)((u + kRing - 1) % kRing) * kHSlot
                                        + (size_t)arow * kH + koff;
            short8 a[16];
#pragma unroll
            for (int kk = 0; kk < 16; ++kk) a[kk] = *(const short8*)(hp2 + kk * 32);
#pragma unroll
            for (int kk = 0; kk < 16; ++kk) {
#pragma unroll
                for (int gg = 0; gg < 4; ++gg) {
                    short8 b = *(const short8*)&lw[((64 + gg * 16 + kk) << 9) + (lane << 3)];
                    acc[gg] = __builtin_amdgcn_mfma_f32_16x16x32_bf16(a[kk], b, acc[gg], 0, 0, 0);
                }
            }

            waitf(f1, u + 1, lane, fc1);                // L1 done step u

            const unsigned short* hp1 = h1r + (size_t)(u % kRing) * kHSlot
                                        + (size_t)arow * kH + koff;   // h1[u]
#pragma unroll
            for (int kk = 0; kk < 16; ++kk) a[kk] = *(const short8*)(hp1 + kk * 32);
#pragma unroll
            for (int kk = 0; kk < 16; ++kk) {
#pragma unroll
                for (int gg = 0; gg < 4; ++gg) {
                    short8 b = *(const short8*)&lw[((gg * 16 + kk) << 9) + (lane << 3)];
                    acc[gg] = __builtin_amdgcn_mfma_f32_16x16x32_bf16(a[kk], b, acc[gg], 0, 0, 0);
                }
            }

            unsigned short* hw = h2r + (size_t)(u % kRing) * kHSlot;
            const int j = j0 + lcol;
#pragma unroll
            for (int r = 0; r < 4; ++r) {
                int row = quad * 4 + r;
                float gi = acc[0][r], gf = acc[1][r], ggv = acc[2][r], go = acc[3][r];
                float cn = sigm(gf) * creg[r] + sigm(gi) * tanh_(ggv);
                float hn = sigm(go) * tanh_(cn);
                creg[r] = cn;
                scr[row * 24 + lcol] = f2bf(hn);
                if (u == kSeq - 1) h2f[(size_t)(m0 + row) * kH + j] = hn;
            }
            if (lane < 32) {
                int row = lane >> 1, seg = lane & 1;
                short8 v = *(short8*)&scr[row * 24 + seg * 8];
                unsigned short* gp = hw + (size_t)(m0 + row) * kH + j0 + seg * 8;
                LLC_STORE16(gp, v);
            }
            __builtin_amdgcn_s_waitcnt(0);
            __syncthreads();
            if (tid == 0)
                __hip_atomic_store(myflag, u + 1,
                                   __ATOMIC_RELAXED, __HIP_MEMORY_SCOPE_AGENT);
        }
    }
}

__global__ __launch_bounds__(64) void k_head(
    const float* __restrict__ h2f, const float* __restrict__ fc1w,
    const float* __restrict__ fc1b, const float* __restrict__ fcw,
    const float* __restrict__ fcb, float* __restrict__ out)
{
    int m = blockIdx.x;
    int j = threadIdx.x;
    const float* hr = h2f + (size_t)m * kH;
    const float* wr = fc1w + (size_t)j * kH;
    float sacc = 0.f;
    for (int k = 0; k < kH; ++k) sacc += fmaxf(hr[k], 0.f) * wr[k];
    float rv = fmaxf(sacc + fc1b[j], 0.f) * fcw[j];
#pragma unroll
    for (int off = 32; off >= 1; off >>= 1) rv += __shfl_down(rv, off);
    if (j == 0) out[m] = 2.0f * (rv + fcb[0]);
}

extern "C" void kernel_launch(void* const* d_in, const int* in_sizes, int n_in,
                              void* d_out, int out_size, void* d_ws, size_t ws_size,
                              hipStream_t stream) {
    const float* x    = (const float*)d_in[0];
    const float* Wih1 = (const float*)d_in[1];
    const float* Whh1 = (const float*)d_in[2];
    const float* bih1 = (const float*)d_in[3];
    const float* bhh1 = (const float*)d_in[4];
    const float* Wih2 = (const float*)d_in[5];
    const float* Whh2 = (const float*)d_in[6];
    const float* bih2 = (const float*)d_in[7];
    const float* bhh2 = (const float*)d_in[8];
    const float* fc1w = (const float*)d_in[9];
    const float* fc1b = (const float*)d_in[10];
    const float* fcw  = (const float*)d_in[11];
    const float* fcb  = (const float*)d_in[12];
    float* out = (float*)d_out;

    char* p = (char*)d_ws;
    auto take = [&](size_t bytes) -> char* {
        char* r = p;
        p += (bytes + 255) & ~(size_t)255;
        return r;
    };
    unsigned short* whh1b = (unsigned short*)take((size_t)kG * kH * 2);
    unsigned short* wih2b = (unsigned short*)take((size_t)kG * kH * 2);
    unsigned short* whh2b = (unsigned short*)take((size_t)kG * kH * 2);
    unsigned short* wih1b = (unsigned short*)take((size_t)kG * 32 * 2);
    unsigned short* xb    = (unsigned short*)take((size_t)kSeq * kBatch * 32 * 2);
    char* state = p;
    unsigned short* h1r = (unsigned short*)take((size_t)kRing * kHSlot * 2);
    unsigned short* h2r = (unsigned short*)take((size_t)kRing * kHSlot * 2);
    int* flags = (int*)take(16384);
    size_t state_bytes = (size_t)((char*)flags + 16384 - state);
    float* h2f = (float*)take((size_t)kBatch * kH * 4);

    hipMemsetAsync(state, 0, state_bytes, stream);

    int n = kG * kH;
    k_conv<<<(n + 255) / 256, 256, 0, stream>>>(Whh1, whh1b, n);
    k_conv<<<(n + 255) / 256, 256, 0, stream>>>(Wih2, wih2b, n);
    k_conv<<<(n + 255) / 256, 256, 0, stream>>>(Whh2, whh2b, n);
    k_conv_pad<<<(kG * 32 + 255) / 256, 256, 0, stream>>>(Wih1, wih1b, kG);
    k_conv_pad<<<(kSeq * kBatch * 32 + 255) / 256, 256, 0, stream>>>(x, xb, kSeq * kBatch);

    hipFuncSetAttribute((const void*)k_persist,
                        hipFuncAttributeMaxDynamicSharedMemorySize, (int)kShmemBytes);
    void* args[] = {&whh1b, &wih1b, &wih2b, &whh2b, &xb,
                    (void*)&bih1, (void*)&bhh1, (void*)&bih2, (void*)&bhh2,
                    &h1r, &h2r, &h2f, &flags};
    hipError_t e = hipLaunchCooperativeKernel((const void*)k_persist, dim3(256), dim3(256),
                                              args, (unsigned)kShmemBytes, stream);
    if (e != hipSuccess) {
        k_persist<<<256, 256, kShmemBytes, stream>>>(
            whh1b, wih1b, wih2b, whh2b, xb, bih1, bhh1, bih2, bhh2,
            h1r, h2r, h2f, flags);
    }

    k_head<<<kBatch, 64, 0, stream>>>(h2f, fc1w, fc1b, fcw, fcb, out);
}

// Round 14
// 3842.654 us; speedup vs baseline: 2.1458x; 1.0320x over previous
//
#include <hip/hip_runtime.h>
#include <cstdint>
#include <cstddef>

typedef __attribute__((ext_vector_type(8))) short short8;
typedef __attribute__((ext_vector_type(4))) float floatx4;

constexpr int kSeq = 512;
constexpr int kBatch = 256;
constexpr int kIn = 15;
constexpr int kH = 512;
constexpr int kG = 4 * kH;                      // 2048 gate cols, order i,f,g,o
constexpr int kRing = 65;                       // ring depth (> window 64)
constexpr int kWinMask = 63;                    // rendezvous window 64
constexpr size_t kHSlot = (size_t)kBatch * kH;  // elements per h slot
// LDS: 128 KB weights (fragment-linear) + 4 waves * 768 B transpose scratch
constexpr size_t kShmemBytes = 131072 + 4096;

__device__ __forceinline__ unsigned short f2bf(float f) {
    union { float f; unsigned u; } v; v.f = f;
    unsigned u = v.u;
    return (unsigned short)((u + 0x7fffu + ((u >> 16) & 1u)) >> 16);
}

__device__ __forceinline__ float sigm(float x) { return 1.0f / (1.0f + __expf(-x)); }
__device__ __forceinline__ float tanh_(float x) { return 1.0f - 2.0f / (1.0f + __expf(2.0f * x)); }

// 16-B write-through store (LLC always current; h never dirty in any L2)
#define LLC_STORE16(P, V)                                                     \
    asm volatile("global_store_dwordx4 %0, %1, off sc0 sc1"                   \
                 :: "v"(P), "v"(V) : "memory")

// ALL-WAVE poll with BOUNDED busy-spin (r5-proven): every wave independently
// watches the 32 flags (lanes 0..31, one 64B line each). Spin minimizes
// observe granularity; past 4096 iterations degrade to s_sleep(8) so
// pathological regimes are self-limiting. fc caches the monotone flag —
// a satisfied wait does zero memory ops. No broadcast barrier needed.
__device__ __forceinline__ void waitf(const int* flags, int tgt, int lane, int& fc) {
    if (tgt <= 0) return;
    bool watch = (lane < 32);
    if (__all(!watch || fc >= tgt)) return;
    int spin = 0;
    for (;;) {
        if (watch && fc < tgt)
            fc = __hip_atomic_load(flags + lane * 16,
                                   __ATOMIC_RELAXED, __HIP_MEMORY_SCOPE_AGENT);
        if (__all(!watch || fc >= tgt)) return;
        if (++spin > 4096) __builtin_amdgcn_s_sleep(8);
    }
}

__global__ void k_conv(const float* __restrict__ src, unsigned short* __restrict__ dst, int n) {
    int i = blockIdx.x * blockDim.x + threadIdx.x;
    if (i < n) dst[i] = f2bf(src[i]);
}

__global__ void k_conv_pad(const float* __restrict__ src, unsigned short* __restrict__ dst, int rows) {
    int i = blockIdx.x * blockDim.x + threadIdx.x;
    if (i >= rows * 32) return;
    int r = i >> 5, k = i & 31;
    dst[i] = (k < kIn) ? f2bf(src[r * kIn + k]) : (unsigned short)0;
}

// Persistent kernel (r5 skeleton, window 64 / ring 65; r13 validated the
// window knob: each rendezvous costs ~11.6 µs, halving their count won 186).
// group g = blockIdx&3 (64 batch rows, 2-XCD-affine under RR dispatch);
// role = blockIdx>>2: 0..31 layer-1, 32..63 layer-2 (16 h-cols each).
// h1/h2: 65-slot rings. Producers: sc0sc1 write-through. Consumers: PLAIN
// CACHED loads (redundancy absorbed by per-XCD L2/L1), made safe by a
// group rendezvous + agent acquire fence every 64 steps:
//   - rendezvous at boundary B waits f1>=B && f2>=B  => all reads for steps
//     <B are complete before any fence, and inter-layer skew is bounded <64;
//   - any two reads of the same ring address are >=65 steps apart (ring 65),
//     and a multiple-of-64 boundary always falls between them, so each
//     reader fences between old-value and new-value reads; ring 65 > skew
//     bound 64 => no slot is overwritten while still readable.
// Flags: one per 64B line (f1[32] @ +0, stride 16 ints; f2 @ +512 ints).
// All waves poll independently — the only per-step block barrier is the one
// before the tid==0 flag publish (all waves' stores must be drained first).
__global__ __launch_bounds__(256) void k_persist(
    const unsigned short* __restrict__ whh1b,
    const unsigned short* __restrict__ wih1b,
    const unsigned short* __restrict__ wih2b,
    const unsigned short* __restrict__ whh2b,
    const unsigned short* __restrict__ xb,
    const float* __restrict__ bih1, const float* __restrict__ bhh1,
    const float* __restrict__ bih2, const float* __restrict__ bhh2,
    unsigned short* __restrict__ h1r,   // kRing slots of kBatch*kH
    unsigned short* __restrict__ h2r,   // kRing slots of kBatch*kH
    float* __restrict__ h2f,
    int* __restrict__ flags)            // per group: f1[32] @ +0, f2[32] @ +512 ints
{
    extern __shared__ unsigned short lw[];
    const int bid = blockIdx.x;
    const int g = bid & 3;
    const int role = bid >> 2;
    const bool is2 = role >= 32;
    const int rid = role & 31;
    const int j0 = rid << 4;
    const int tid = (int)threadIdx.x;
    const int wave = tid >> 6;
    const int lane = tid & 63;
    const int lcol = lane & 15;
    const int quad = lane >> 4;
    const int m0 = (g << 6) + wave * 16;
    const int arow = m0 + lcol;
    const int koff = quad * 8;

    int* f1 = flags + g * 1024;
    int* f2 = f1 + 512;
    int* myflag = (is2 ? f2 : f1) + rid * 16;
    unsigned short* scr = lw + 65536 + wave * 384;   // 16 rows x stride-24 elems

    // ---- stage weight slices into LDS, fragment-linear layout ----
    if (!is2) {
        for (int i = tid; i < 4096; i += 256) {
            int ln = i >> 6, gg = ln >> 4, u = ln & 15;
            int c = i & 63, kk = c >> 2, qd = c & 3;
            *(short8*)&lw[((gg * 16 + kk) << 9) + ((qd * 16 + u) << 3)] =
                *(const short8*)&whh1b[(size_t)((gg << 9) + j0 + u) * kH + c * 8];
        }
        for (int i = tid; i < 256; i += 256) {
            int ln = i >> 2, gg = ln >> 4, u = ln & 15;
            int qd = i & 3;
            *(short8*)&lw[((64 + gg) << 9) + ((qd * 16 + u) << 3)] =
                *(const short8*)&wih1b[((gg << 9) + j0 + u) * 32 + qd * 8];
        }
    } else {
        for (int i = tid; i < 4096; i += 256) {
            int ln = i >> 6, gg = ln >> 4, u = ln & 15;
            int c = i & 63, kk = c >> 2, qd = c & 3;
            int dst = ((gg * 16 + kk) << 9) + ((qd * 16 + u) << 3);
            size_t src = (size_t)((gg << 9) + j0 + u) * kH + c * 8;
            *(short8*)&lw[dst] = *(const short8*)&wih2b[src];
            *(short8*)&lw[dst + (64 << 9)] = *(const short8*)&whh2b[src];
        }
    }
    float bsum[4];
#pragma unroll
    for (int gg = 0; gg < 4; ++gg) {
        int n = (gg << 9) + j0 + lcol;
        bsum[gg] = is2 ? (bih2[n] + bhh2[n]) : (bih1[n] + bhh1[n]);
    }
    __syncthreads();

    float creg[4] = {0.f, 0.f, 0.f, 0.f};
    int fc1 = 0, fc2 = 0;   // per-thread flag caches

    if (!is2) {
        for (int s = 0; s < kSeq; ++s) {
            if ((s & kWinMask) == 0) {   // window rendezvous + cache invalidate
                waitf(f1, s, lane, fc1);
                waitf(f2, s, lane, fc2);
                __builtin_amdgcn_fence(__ATOMIC_ACQUIRE, "agent");
            }
            floatx4 acc[4];
#pragma unroll
            for (int gg = 0; gg < 4; ++gg)
                acc[gg] = (floatx4){bsum[gg], bsum[gg], bsum[gg], bsum[gg]};

            short8 ax = *(const short8*)(xb + ((size_t)s * kBatch + arow) * 32 + koff);

            waitf(f1, s, lane, fc1);                    // peers done s-1
            const unsigned short* hp = h1r + (size_t)((s + kRing - 1) % kRing) * kHSlot
                                       + (size_t)arow * kH + koff;   // h1[s-1]
            short8 a[16];
#pragma unroll
            for (int kk = 0; kk < 16; ++kk) a[kk] = *(const short8*)(hp + kk * 32);
#pragma unroll
            for (int kk = 0; kk < 16; ++kk) {
#pragma unroll
                for (int gg = 0; gg < 4; ++gg) {
                    short8 b = *(const short8*)&lw[((gg * 16 + kk) << 9) + (lane << 3)];
                    acc[gg] = __builtin_amdgcn_mfma_f32_16x16x32_bf16(a[kk], b, acc[gg], 0, 0, 0);
                }
            }
#pragma unroll
            for (int gg = 0; gg < 4; ++gg) {
                short8 b = *(const short8*)&lw[((64 + gg) << 9) + (lane << 3)];
                acc[gg] = __builtin_amdgcn_mfma_f32_16x16x32_bf16(ax, b, acc[gg], 0, 0, 0);
            }

            // epilogue: activations -> per-wave LDS transpose -> 16B WT stores
            // (scr is wave-private: compiler's lgkmcnt orders write->read)
            unsigned short* hw = h1r + (size_t)(s % kRing) * kHSlot;
#pragma unroll
            for (int r = 0; r < 4; ++r) {
                int row = quad * 4 + r;
                float gi = acc[0][r], gf = acc[1][r], ggv = acc[2][r], go = acc[3][r];
                float cn = sigm(gf) * creg[r] + sigm(gi) * tanh_(ggv);
                float hn = sigm(go) * tanh_(cn);
                creg[r] = cn;
                scr[row * 24 + lcol] = f2bf(hn);
            }
            if (lane < 32) {
                int row = lane >> 1, seg = lane & 1;
                short8 v = *(short8*)&scr[row * 24 + seg * 8];
                unsigned short* gp = hw + (size_t)(m0 + row) * kH + j0 + seg * 8;
                LLC_STORE16(gp, v);
            }
            __builtin_amdgcn_s_waitcnt(0);
            __syncthreads();
            if (tid == 0)
                __hip_atomic_store(myflag, s + 1,
                                   __ATOMIC_RELAXED, __HIP_MEMORY_SCOPE_AGENT);
        }
    } else {
        for (int u = 0; u < kSeq; ++u) {
            if ((u & kWinMask) == 0) {   // window rendezvous + cache invalidate
                waitf(f1, u, lane, fc1);
                waitf(f2, u, lane, fc2);
                __builtin_amdgcn_fence(__ATOMIC_ACQUIRE, "agent");
            }
            floatx4 acc[4];
#pragma unroll
            for (int gg = 0; gg < 4; ++gg)
                acc[gg] = (floatx4){bsum[gg], bsum[gg], bsum[gg], bsum[gg]};

            waitf(f2, u, lane, fc2);                    // peers done u-1

            // h2[u-1] GEMM first (hides under L1's tail)
            const unsigned short* hp2 = h2r + (size_t)((u + kRing - 1) % kRing) * kHSlot
                                        + (size_t)arow * kH + koff;
            short8 a[16];
#pragma unroll
            for (int kk = 0; kk < 16; ++kk) a[kk] = *(const short8*)(hp2 + kk * 32);
#pragma unroll
            for (int kk = 0; kk < 16; ++kk) {
#pragma unroll
                for (int gg = 0; gg < 4; ++gg) {
                    short8 b = *(const short8*)&lw[((64 + gg * 16 + kk) << 9) + (lane << 3)];
                    acc[gg] = __builtin_amdgcn_mfma_f32_16x16x32_bf16(a[kk], b, acc[gg], 0, 0, 0);
                }
            }

            waitf(f1, u + 1, lane, fc1);                // L1 done step u

            const unsigned short* hp1 = h1r + (size_t)(u % kRing) * kHSlot
                                        + (size_t)arow * kH + koff;   // h1[u]
#pragma unroll
            for (int kk = 0; kk < 16; ++kk) a[kk] = *(const short8*)(hp1 + kk * 32);
#pragma unroll
            for (int kk = 0; kk < 16; ++kk) {
#pragma unroll
                for (int gg = 0; gg < 4; ++gg) {
                    short8 b = *(const short8*)&lw[((gg * 16 + kk) << 9) + (lane << 3)];
                    acc[gg] = __builtin_amdgcn_mfma_f32_16x16x32_bf16(a[kk], b, acc[gg], 0, 0, 0);
                }
            }

            unsigned short* hw = h2r + (size_t)(u % kRing) * kHSlot;
            const int j = j0 + lcol;
#pragma unroll
            for (int r = 0; r < 4; ++r) {
                int row = quad * 4 + r;
                float gi = acc[0][r], gf = acc[1][r], ggv = acc[2][r], go = acc[3][r];
                float cn = sigm(gf) * creg[r] + sigm(gi) * tanh_(ggv);
                float hn = sigm(go) * tanh_(cn);
                creg[r] = cn;
                scr[row * 24 + lcol] = f2bf(hn);
                if (u == kSeq - 1) h2f[(size_t)(m0 + row) * kH + j] = hn;
            }
            if (lane < 32) {
                int row = lane >> 1, seg = lane & 1;
                short8 v = *(short8*)&scr[row * 24 + seg * 8];
                unsigned short* gp = hw + (size_t)(m0 + row) * kH + j0 + seg * 8;
                LLC_STORE16(gp, v);
            }
            __builtin_amdgcn_s_waitcnt(0);
            __syncthreads();
            if (tid == 0)
                __hip_atomic_store(myflag, u + 1,
                                   __ATOMIC_RELAXED, __HIP_MEMORY_SCOPE_AGENT);
        }
    }
}

__global__ __launch_bounds__(64) void k_head(
    const float* __restrict__ h2f, const float* __restrict__ fc1w,
    const float* __restrict__ fc1b, const float* __restrict__ fcw,
    const float* __restrict__ fcb, float* __restrict__ out)
{
    int m = blockIdx.x;
    int j = threadIdx.x;
    const float* hr = h2f + (size_t)m * kH;
    const float* wr = fc1w + (size_t)j * kH;
    float sacc = 0.f;
    for (int k = 0; k < kH; ++k) sacc += fmaxf(hr[k], 0.f) * wr[k];
    float rv = fmaxf(sacc + fc1b[j], 0.f) * fcw[j];
#pragma unroll
    for (int off = 32; off >= 1; off >>= 1) rv += __shfl_down(rv, off);
    if (j == 0) out[m] = 2.0f * (rv + fcb[0]);
}

extern "C" void kernel_launch(void* const* d_in, const int* in_sizes, int n_in,
                              void* d_out, int out_size, void* d_ws, size_t ws_size,
                              hipStream_t stream) {
    const float* x    = (const float*)d_in[0];
    const float* Wih1 = (const float*)d_in[1];
    const float* Whh1 = (const float*)d_in[2];
    const float* bih1 = (const float*)d_in[3];
    const float* bhh1 = (const float*)d_in[4];
    const float* Wih2 = (const float*)d_in[5];
    const float* Whh2 = (const float*)d_in[6];
    const float* bih2 = (const float*)d_in[7];
    const float* bhh2 = (const float*)d_in[8];
    const float* fc1w = (const float*)d_in[9];
    const float* fc1b = (const float*)d_in[10];
    const float* fcw  = (const float*)d_in[11];
    const float* fcb  = (const float*)d_in[12];
    float* out = (float*)d_out;

    char* p = (char*)d_ws;
    auto take = [&](size_t bytes) -> char* {
        char* r = p;
        p += (bytes + 255) & ~(size_t)255;
        return r;
    };
    unsigned short* whh1b = (unsigned short*)take((size_t)kG * kH * 2);
    unsigned short* wih2b = (unsigned short*)take((size_t)kG * kH * 2);
    unsigned short* whh2b = (unsigned short*)take((size_t)kG * kH * 2);
    unsigned short* wih1b = (unsigned short*)take((size_t)kG * 32 * 2);
    unsigned short* xb    = (unsigned short*)take((size_t)kSeq * kBatch * 32 * 2);
    char* state = p;
    unsigned short* h1r = (unsigned short*)take((size_t)kRing * kHSlot * 2);
    unsigned short* h2r = (unsigned short*)take((size_t)kRing * kHSlot * 2);
    int* flags = (int*)take(16384);
    size_t state_bytes = (size_t)((char*)flags + 16384 - state);
    float* h2f = (float*)take((size_t)kBatch * kH * 4);

    hipMemsetAsync(state, 0, state_bytes, stream);

    int n = kG * kH;
    k_conv<<<(n + 255) / 256, 256, 0, stream>>>(Whh1, whh1b, n);
    k_conv<<<(n + 255) / 256, 256, 0, stream>>>(Wih2, wih2b, n);
    k_conv<<<(n + 255) / 256, 256, 0, stream>>>(Whh2, whh2b, n);
    k_conv_pad<<<(kG * 32 + 255) / 256, 256, 0, stream>>>(Wih1, wih1b, kG);
    k_conv_pad<<<(kSeq * kBatch * 32 + 255) / 256, 256, 0, stream>>>(x, xb, kSeq * kBatch);

    hipFuncSetAttribute((const void*)k_persist,
                        hipFuncAttributeMaxDynamicSharedMemorySize, (int)kShmemBytes);
    void* args[] = {&whh1b, &wih1b, &wih2b, &whh2b, &xb,
                    (void*)&bih1, (void*)&bhh1, (void*)&bih2, (void*)&bhh2,
                    &h1r, &h2r, &h2f, &flags};
    hipError_t e = hipLaunchCooperativeKernel((const void*)k_persist, dim3(256), dim3(256),
                                              args, (unsigned)kShmemBytes, stream);
    if (e != hipSuccess) {
        k_persist<<<256, 256, kShmemBytes, stream>>>(
            whh1b, wih1b, wih2b, whh2b, xb, bih1, bhh1, bih2, bhh2,
            h1r, h2r, h2f, flags);
    }

    k_head<<<kBatch, 64, 0, stream>>>(h2f, fc1w, fc1b, fcw, fcb, out);
}